// Round 2
// baseline (541.328 us; speedup 1.0000x reference)
//
#include <hip/hip_runtime.h>
#include <stdint.h>

#define NROWS 32768   // B*H*W
#define CDIM  512
#define KCODES 1024
#define VC    512

typedef unsigned short u16;
typedef unsigned long long u64;
using bf16x8 = __attribute__((ext_vector_type(8))) __bf16;
using f32x4  = __attribute__((ext_vector_type(4))) float;

__device__ __forceinline__ float bf2f(u16 u){
  union { unsigned int i; float f; } x; x.i = ((unsigned int)u) << 16; return x.f;
}
__device__ __forceinline__ u16 f2bf(float f){
  union { float f; unsigned int i; } x; x.f = f;
  unsigned int u = x.i;
  u += 0x7fffu + ((u >> 16) & 1u);   // RNE
  return (u16)(u >> 16);
}
__device__ __forceinline__ unsigned int pack2(u16 lo, u16 hi){
  return (unsigned int)lo | ((unsigned int)hi << 16);
}
__device__ __forceinline__ unsigned int fkey(float f){
  unsigned int u = __float_as_uint(f);
  return (u & 0x80000000u) ? ~u : (u | 0x80000000u);   // monotone sortable
}
__device__ __forceinline__ f32x4 mfma16(bf16x8 a, bf16x8 b, f32x4 c){
  return __builtin_amdgcn_mfma_f32_16x16x32_bf16(a, b, c, 0, 0, 0);
}
// async global->LDS, 16B per lane; LDS dest is wave-uniform base + lane*16
__device__ __forceinline__ void gload_lds16(const void* g, void* l){
  __builtin_amdgcn_global_load_lds(
      (const __attribute__((address_space(1))) unsigned int*)g,
      (__attribute__((address_space(3))) unsigned int*)l, 16, 0, 0);
}

// ---------------- K1: transpose x (B,C,H,W) -> xf bf16 (N=32768, C=512) ---
__global__ __launch_bounds__(256) void k_transpose_x(const float* __restrict__ x,
                                                     u16* __restrict__ xf){
  __shared__ float tile[32][33];
  int b  = blockIdx.z;
  int p0 = blockIdx.x * 32;
  int c0 = blockIdx.y * 32;
  int tx = threadIdx.x, ty = threadIdx.y;   // (32, 8)
  const float* xb = x + (size_t)b * CDIM * 4096;
#pragma unroll
  for (int i = 0; i < 4; i++){
    int c = c0 + ty + i * 8;
    tile[ty + i * 8][tx] = xb[(size_t)c * 4096 + p0 + tx];
  }
  __syncthreads();
#pragma unroll
  for (int i = 0; i < 4; i++){
    int p = p0 + ty + i * 8;
    xf[((size_t)(b * 4096 + p)) * CDIM + c0 + tx] = f2bf(tile[tx][ty + i * 8]);
  }
}

// ---------------- K2: per-row 1/||x|| from xf bf16 ------------------------
__global__ __launch_bounds__(256) void k_rownorm(const u16* __restrict__ xf,
                                                 float* __restrict__ rinv){
  int row  = blockIdx.x * 4 + (threadIdx.x >> 6);
  int lane = threadIdx.x & 63;
  const uint4* p = (const uint4*)(xf + (size_t)row * CDIM);
  uint4 v = p[lane];
  unsigned int w[4] = {v.x, v.y, v.z, v.w};
  float s = 0.f;
#pragma unroll
  for (int i = 0; i < 4; i++){
    float a = bf2f((u16)(w[i] & 0xffffu));
    float b = bf2f((u16)(w[i] >> 16));
    s += a * a + b * b;
  }
#pragma unroll
  for (int off = 32; off; off >>= 1) s += __shfl_xor(s, off, 64);
  if (lane == 0) rinv[row] = 1.0f / fmaxf(sqrtf(s), 1e-12f);
}

// ---------------- K3: normalize noise_feature rows -> mn bf16 -------------
__global__ __launch_bounds__(256) void k_norm_rows(const float* __restrict__ in,
                                                   u16* __restrict__ out){
  int row  = blockIdx.x * 4 + (threadIdx.x >> 6);
  int lane = threadIdx.x & 63;
  const float* r = in + (size_t)row * CDIM;
  float v[8]; float s = 0.f;
#pragma unroll
  for (int i = 0; i < 8; i++){ v[i] = r[lane + i * 64]; s += v[i] * v[i]; }
#pragma unroll
  for (int off = 32; off; off >>= 1) s += __shfl_xor(s, off, 64);
  float inv = 1.0f / fmaxf(sqrtf(s), 1e-12f);
#pragma unroll
  for (int i = 0; i < 8; i++) out[(size_t)row * CDIM + lane + i * 64] = f2bf(v[i] * inv);
}

// ---------------- K3b: transpose std (1024,512) -> stdT bf16 (512,1024) ---
__global__ __launch_bounds__(256) void k_transpose_std(const float* __restrict__ sd,
                                                       u16* __restrict__ stdT){
  __shared__ float tile[32][33];
  int k0 = blockIdx.x * 32;
  int v0 = blockIdx.y * 32;
  int tx = threadIdx.x, ty = threadIdx.y;
#pragma unroll
  for (int i = 0; i < 4; i++)
    tile[ty + i * 8][tx] = sd[(size_t)(k0 + ty + i * 8) * VC + v0 + tx];
  __syncthreads();
#pragma unroll
  for (int i = 0; i < 4; i++)
    stdT[(size_t)(v0 + ty + i * 8) * KCODES + k0 + tx] = f2bf(tile[tx][ty + i * 8]);
}

// ---------------- K4: GEMM1 (xf @ mn^T) + packed atomicMax argmax ---------
__global__ __launch_bounds__(256) void k_gemm1_am(const u16* __restrict__ xf,
                                                  const u16* __restrict__ mn,
                                                  u64* __restrict__ packed){
  __shared__ u16 As[128 * 64];
  __shared__ u16 Bs[128 * 64];
  int tid  = threadIdx.x;
  int wave = tid >> 6, lane = tid & 63;
  int wr = wave >> 1, wc = wave & 1;
  int quad = lane >> 4, l15 = lane & 15;
  int c0 = blockIdx.x * 128, r0 = blockIdx.y * 128;

  int srow = lane >> 3, schunk = lane & 7;
  const u16* ag = xf + (size_t)(r0 + wave * 8 + srow) * CDIM + schunk * 8;
  const u16* bg = mn + (size_t)(c0 + wave * 8 + srow) * CDIM + schunk * 8;
  u16* adst = As + wave * 8 * 64;
  u16* bdst = Bs + wave * 8 * 64;

  f32x4 acc[4][4];
#pragma unroll
  for (int rt = 0; rt < 4; rt++)
#pragma unroll
    for (int ct = 0; ct < 4; ct++) acc[rt][ct] = (f32x4)(0.f);

  for (int k0 = 0; k0 < CDIM; k0 += 64){
#pragma unroll
    for (int i = 0; i < 4; i++){
      gload_lds16(ag + (size_t)i * 32 * CDIM + k0, adst + i * 32 * 64);
      gload_lds16(bg + (size_t)i * 32 * CDIM + k0, bdst + i * 32 * 64);
    }
    __syncthreads();
#pragma unroll
    for (int ks = 0; ks < 2; ks++){
      bf16x8 af[4], bfr[4];
#pragma unroll
      for (int rt = 0; rt < 4; rt++)
        af[rt] = *(const bf16x8*)(As + (wr * 64 + rt * 16 + l15) * 64 + ks * 32 + quad * 8);
#pragma unroll
      for (int ct = 0; ct < 4; ct++)
        bfr[ct] = *(const bf16x8*)(Bs + (wc * 64 + ct * 16 + l15) * 64 + ks * 32 + quad * 8);
#pragma unroll
      for (int rt = 0; rt < 4; rt++)
#pragma unroll
        for (int ct = 0; ct < 4; ct++)
          acc[rt][ct] = mfma16(af[rt], bfr[ct], acc[rt][ct]);
    }
    __syncthreads();
  }

#pragma unroll
  for (int rt = 0; rt < 4; rt++){
#pragma unroll
    for (int q = 0; q < 4; q++){
      float bv = acc[rt][0][q];
      int   bc = c0 + wc * 64 + l15;
#pragma unroll
      for (int ct = 1; ct < 4; ct++){
        float v = acc[rt][ct][q];
        int   c = c0 + wc * 64 + ct * 16 + l15;
        if (v > bv){ bv = v; bc = c; }          // ascending c: first wins ties
      }
#pragma unroll
      for (int off = 1; off <= 8; off <<= 1){
        float ov = __shfl_xor(bv, off, 64);
        int   oc = __shfl_xor(bc, off, 64);
        if (ov > bv || (ov == bv && oc < bc)){ bv = ov; bc = oc; }
      }
      if (l15 == 0){
        int rg = r0 + wr * 64 + rt * 16 + quad * 4 + q;
        u64 key = ((u64)fkey(bv) << 32) | (unsigned int)(~(unsigned int)bc);
        atomicMax(packed + rg, key);
      }
    }
  }
}

// ---------------- K5a: decode packed -> embed_ind -------------------------
__global__ __launch_bounds__(256) void k_decode(const u64* __restrict__ packed,
                                                int* __restrict__ ind){
  int i = blockIdx.x * 256 + threadIdx.x;
  ind[i] = (int)(~(unsigned int)(packed[i] & 0xffffffffull)) & (KCODES - 1);
}

// ---------------- K5b: per-code gather segment sum (no atomics) -----------
__global__ __launch_bounds__(256) void k_gather(const int* __restrict__ ind,
                                                const u16* __restrict__ xf,
                                                float* __restrict__ esum,
                                                float* __restrict__ counts){
  __shared__ float part[4][CDIM];   // 8 KB
  __shared__ int   wcnt[4];
  int code = blockIdx.x;
  int tid = threadIdx.x, wave = tid >> 6, lane = tid & 63;
  float acc[8] = {0,0,0,0,0,0,0,0};
  int cnt = 0;
  for (int base = wave * 64; base < NROWS; base += 256){
    int match = (ind[base + lane] == code);
    u64 mask = __ballot(match);
    cnt += (int)__popcll(mask);
    while (mask){
      int b = __ffsll((long long)mask) - 1;
      mask &= mask - 1;
      int rr = base + b;
      uint4 v = *(const uint4*)(xf + (size_t)rr * CDIM + lane * 8);
      unsigned int w[4] = {v.x, v.y, v.z, v.w};
#pragma unroll
      for (int i = 0; i < 4; i++){
        acc[2 * i]     += bf2f((u16)(w[i] & 0xffffu));
        acc[2 * i + 1] += bf2f((u16)(w[i] >> 16));
      }
    }
  }
#pragma unroll
  for (int j = 0; j < 8; j++) part[wave][lane * 8 + j] = acc[j];
  if (lane == 0) wcnt[wave] = cnt;
  __syncthreads();
  for (int c = tid; c < CDIM; c += 256)
    esum[(size_t)code * CDIM + c] = part[0][c] + part[1][c] + part[2][c] + part[3][c];
  if (tid == 0) counts[code] = (float)(wcnt[0] + wcnt[1] + wcnt[2] + wcnt[3]);
}

// ---------------- K6: new_m = m*0.999 + mean*0.001; normalize -> mn2 bf16 -
__global__ __launch_bounds__(256) void k_newm(const float* __restrict__ m,
                                              const float* __restrict__ esum,
                                              const float* __restrict__ counts,
                                              u16* __restrict__ mn2){
  int row  = blockIdx.x * 4 + (threadIdx.x >> 6);
  int lane = threadIdx.x & 63;
  float cnt = counts[row];
  float sc  = 0.001f / (cnt + 1e-6f);
  float v[8]; float s = 0.f;
#pragma unroll
  for (int i = 0; i < 8; i++){
    int c = lane + i * 64;
    v[i] = m[(size_t)row * CDIM + c] * 0.999f + esum[(size_t)row * CDIM + c] * sc;
    s += v[i] * v[i];
  }
#pragma unroll
  for (int off = 32; off; off >>= 1) s += __shfl_xor(s, off, 64);
  float inv = 1.0f / fmaxf(sqrtf(s), 1e-12f);
#pragma unroll
  for (int i = 0; i < 8; i++) mn2[(size_t)row * CDIM + lane + i * 64] = f2bf(v[i] * inv);
}

// ---------------- K7: FUSED gemm2 + softmax + gemm3 (flash-style) ---------
// Per block: 64 rows. LDS: As 64x512 bf16 (swz, loaded once), per tile of 32
// codes: Bs(mn2) 32x512 bf16 (swz), Vs(stdT) 512x32 bf16 (swz), Sf 64x36 f32,
// Pt 64x32 bf16 (swz), row stats. Writes raw score2 tile + accumulates
// O = softmax(score2) @ std with online rescale. 512 threads / 8 waves.
#define SM_AS   0          // 65536
#define SM_BS   65536      // 32768
#define SM_VS   98304      // 32768
#define SM_SF   131072     // 64*36*4 = 9216
#define SM_PT   140288     // 4096
#define SM_RM   144384     // 256
#define SM_RL   144640     // 256
#define SM_RS   144896     // 256  -> total 145152
__global__ __launch_bounds__(512) void k_fused(const u16* __restrict__ xf,
                                               const u16* __restrict__ mn2,
                                               const float* __restrict__ rinv,
                                               const u16* __restrict__ stdT,
                                               float* __restrict__ score2,
                                               float* __restrict__ out){
  __shared__ char smem[145152];
  char* AsB = smem + SM_AS;
  char* BsB = smem + SM_BS;
  char* VsB = smem + SM_VS;
  float* Sf = (float*)(smem + SM_SF);
  char* PtB = smem + SM_PT;
  float* rowm = (float*)(smem + SM_RM);
  float* rowl = (float*)(smem + SM_RL);
  float* rowsc = (float*)(smem + SM_RS);

  int tid  = threadIdx.x;
  int wave = tid >> 6, lane = tid & 63;
  int quad = lane >> 4, l15 = lane & 15;
  int r0 = blockIdx.x * 64;

  // S-phase frag ownership: 4 row-tiles x 2 code-tiles = 8 frags = 8 waves
  int fr = wave >> 1, fc = wave & 1;
  int ar = fr * 16 + l15;          // xf row (within block) this lane reads
  int br = fc * 16 + l15;          // mn2 row (within tile) this lane reads

  // PV wave tiling: 2 row-groups x 4 col-groups
  int wr2 = wave >> 2, wc4 = wave & 3;
  int R = wr2 * 32, C = wc4 * 128;

  // stats-phase role
  int srow = tid >> 3, ssub = tid & 7;
  float rv = rinv[r0 + srow];

  f32x4 acc[2][8];
#pragma unroll
  for (int rt = 0; rt < 2; rt++)
#pragma unroll
    for (int ct = 0; ct < 8; ct++) acc[rt][ct] = (f32x4)(0.f);

  // ---- prologue: stage As (once), Bs(0), Vs(0) ----
#pragma unroll
  for (int i = 0; i < 8; i++){
    int rr = wave * 8 + i;
    gload_lds16(xf + (size_t)(r0 + rr) * CDIM + ((lane ^ (rr & 7)) * 8),
                AsB + rr * 1024);
  }
#pragma unroll
  for (int i = 0; i < 4; i++){
    int rr = wave + i * 8;
    gload_lds16(mn2 + (size_t)rr * CDIM + ((lane ^ (rr & 7)) * 8),
                BsB + rr * 1024);
  }
#pragma unroll
  for (int i = 0; i < 4; i++){
    int vb = (wave * 4 + i) * 16;
    int vc = vb + (lane >> 2);
    gload_lds16(stdT + (size_t)vc * KCODES + (((lane & 3) ^ (vc & 3)) * 8),
                VsB + vb * 64);
  }
  if (tid < 64){ rowm[tid] = -3.0e38f; rowl[tid] = 0.f; }
  asm volatile("s_waitcnt vmcnt(0)" ::: "memory");
  __syncthreads();

  for (int t = 0; t < 32; ++t){
    int kt = t * 32;
    // ---- S phase: 16x16 frag over K=512 ----
    f32x4 sacc = (f32x4)(0.f);
#pragma unroll
    for (int ks = 0; ks < 16; ++ks){
      bf16x8 a = *(const bf16x8*)(AsB + ar * 1024 + (((ks * 4 + quad) ^ (ar & 7)) << 4));
      bf16x8 b = *(const bf16x8*)(BsB + br * 1024 + (((ks * 4 + quad) ^ (br & 7)) << 4));
      sacc = mfma16(a, b, sacc);
    }
#pragma unroll
    for (int q = 0; q < 4; ++q)
      Sf[(fr * 16 + quad * 4 + q) * 36 + fc * 16 + l15] = sacc[q];
    // B1: Sf visible; Bs consumed
    asm volatile("s_waitcnt lgkmcnt(0)" ::: "memory");
    __builtin_amdgcn_s_barrier();
    // stage Bs(t+1) (overlaps stats + PV)
    if (t + 1 < 32){
#pragma unroll
      for (int i = 0; i < 4; i++){
        int rr = wave + i * 8;
        gload_lds16(mn2 + (size_t)(kt + 32 + rr) * CDIM + ((lane ^ (rr & 7)) * 8),
                    BsB + rr * 1024);
      }
    }
    // ---- stats: score2 write + online softmax + P(bf16) ----
    {
      f32x4 v = *(const f32x4*)(Sf + srow * 36 + ssub * 4);
      v *= rv;
      *(f32x4*)(score2 + (size_t)(r0 + srow) * KCODES + kt + ssub * 4) = v;
      float mx = fmaxf(fmaxf(v[0], v[1]), fmaxf(v[2], v[3]));
      mx = fmaxf(mx, __shfl_xor(mx, 1, 64));
      mx = fmaxf(mx, __shfl_xor(mx, 2, 64));
      mx = fmaxf(mx, __shfl_xor(mx, 4, 64));
      float mo = rowm[srow];
      float mn_ = fmaxf(mo, mx);
      float d = __expf(mo - mn_);
      float p0 = __expf(v[0] - mn_), p1 = __expf(v[1] - mn_);
      float p2 = __expf(v[2] - mn_), p3 = __expf(v[3] - mn_);
      float ss = p0 + p1 + p2 + p3;
      ss += __shfl_xor(ss, 1, 64);
      ss += __shfl_xor(ss, 2, 64);
      ss += __shfl_xor(ss, 4, 64);
      if (ssub == 0){
        rowl[srow] = rowl[srow] * d + ss;
        rowm[srow] = mn_;
        rowsc[srow] = d;
      }
      uint2 pw;
      pw.x = pack2(f2bf(p0), f2bf(p1));
      pw.y = pack2(f2bf(p2), f2bf(p3));
      *(uint2*)(PtB + srow * 64 + (((ssub >> 1) ^ (srow & 3)) << 4) + ((ssub & 1) << 3)) = pw;
    }
    // B2: Pt/rowsc visible; Vs(t) loaded (leave newest 4 vmem ops in flight)
    asm volatile("s_waitcnt vmcnt(4) lgkmcnt(0)" ::: "memory");
    __builtin_amdgcn_s_barrier();
    __builtin_amdgcn_sched_barrier(0);
    // ---- PV: rescale + accumulate ----
#pragma unroll
    for (int rt = 0; rt < 2; rt++)
#pragma unroll
      for (int q = 0; q < 4; q++){
        float s = rowsc[R + rt * 16 + quad * 4 + q];
#pragma unroll
        for (int ct = 0; ct < 8; ct++) acc[rt][ct][q] *= s;
      }
    bf16x8 pa[2];
#pragma unroll
    for (int rt = 0; rt < 2; rt++){
      int rr = R + rt * 16 + l15;
      pa[rt] = *(const bf16x8*)(PtB + rr * 64 + ((quad ^ (rr & 3)) << 4));
    }
#pragma unroll
    for (int ct = 0; ct < 8; ct++){
      int vc = C + ct * 16 + l15;
      bf16x8 bv = *(const bf16x8*)(VsB + vc * 64 + ((quad ^ (vc & 3)) << 4));
#pragma unroll
      for (int rt = 0; rt < 2; rt++) acc[rt][ct] = mfma16(pa[rt], bv, acc[rt][ct]);
    }
    // B3: Vs consumed
    asm volatile("s_waitcnt lgkmcnt(0)" ::: "memory");
    __builtin_amdgcn_s_barrier();
    // stage Vs(t+1) (overlaps next S phase)
    if (t + 1 < 32){
#pragma unroll
      for (int i = 0; i < 4; i++){
        int vb = (wave * 4 + i) * 16;
        int vc = vb + (lane >> 2);
        gload_lds16(stdT + (size_t)vc * KCODES + kt + 32 + (((lane & 3) ^ (vc & 3)) * 8),
                    VsB + vb * 64);
      }
      // B4: Bs(t+1) ready for next S phase (leave the 4 Vs issues in flight)
      asm volatile("s_waitcnt vmcnt(4)" ::: "memory");
      __builtin_amdgcn_s_barrier();
      __builtin_amdgcn_sched_barrier(0);
    }
  }

  // ---- epilogue: O /= rowsum ----
#pragma unroll
  for (int rt = 0; rt < 2; rt++)
#pragma unroll
    for (int q = 0; q < 4; q++){
      int rr = R + rt * 16 + quad * 4 + q;
      float inv = 1.0f / rowl[rr];
#pragma unroll
      for (int ct = 0; ct < 8; ct++)
        out[(size_t)(r0 + rr) * VC + C + ct * 16 + l15] = acc[rt][ct][q] * inv;
    }
}

// ---------------- launch ---------------------------------------------------
extern "C" void kernel_launch(void* const* d_in, const int* in_sizes, int n_in,
                              void* d_out, int out_size, void* d_ws, size_t ws_size,
                              hipStream_t stream){
  (void)in_sizes; (void)n_in; (void)out_size; (void)ws_size;
  const float* x      = (const float*)d_in[0];
  const float* m      = (const float*)d_in[1];
  const float* stdmat = (const float*)d_in[2];
  float* out    = (float*)d_out;
  float* score2 = out + (size_t)NROWS * VC;     // outputs: (out, score2)

  char* ws = (char*)d_ws;
  u16*   xf     = (u16*)  (ws + 0);             // 33,554,432 B
  u16*   mn     = (u16*)  (ws + 33554432);      //  1,048,576 B
  u16*   mn2    = (u16*)  (ws + 34603008);      //  1,048,576 B
  u16*   stdT   = (u16*)  (ws + 35651584);      //  1,048,576 B
  float* rinv   = (float*)(ws + 36700160);      //    131,072 B
  u64*   packed = (u64*)  (ws + 36831232);      //    262,144 B
  int*   ind    = (int*)  (ws + 37093376);      //    131,072 B
  float* esum   = (float*)(ws + 37224448);      //  2,097,152 B
  float* counts = (float*)(ws + 39321600);      //      4,096 B

  hipMemsetAsync(packed, 0, (size_t)NROWS * 8, stream);  // key=0 is identity

  k_transpose_x  <<<dim3(128, 16, 8), dim3(32, 8), 0, stream>>>(x, xf);
  k_rownorm      <<<NROWS / 4, 256, 0, stream>>>(xf, rinv);
  k_norm_rows    <<<KCODES / 4, 256, 0, stream>>>(m, mn);
  k_transpose_std<<<dim3(32, 16), dim3(32, 8), 0, stream>>>(stdmat, stdT);
  k_gemm1_am     <<<dim3(KCODES / 128, NROWS / 128), 256, 0, stream>>>(xf, mn, packed);
  k_decode       <<<NROWS / 256, 256, 0, stream>>>(packed, ind);
  k_gather       <<<KCODES, 256, 0, stream>>>(ind, xf, esum, counts);
  k_newm         <<<KCODES / 4, 256, 0, stream>>>(m, esum, counts, mn2);
  k_fused        <<<NROWS / 64, 512, 0, stream>>>(xf, mn2, rinv, stdT, score2, out);
}